// Round 3
// baseline (2939.477 us; speedup 1.0000x reference)
//
#include <hip/hip_runtime.h>
#include <float.h>

#define B_  32
#define C_  3
#define H_  64
#define W_  64
#define N_  2048
#define D_  128
#define KNN 8
#define PS  75        // 3*5*5
#define NW  4         // waves per block = dictionary chunks
#define NCHUNK (N_ / NW)   // 512 patches per wave
#define QP  8         // patches per inner iteration (xq reuse factor)

// ---------------------------------------------------------------------------
// Kernel 1: bias[n] = 0.5 * ||patches[n]||^2
// ---------------------------------------------------------------------------
__global__ __launch_bounds__(256) void bias_kernel(const float* __restrict__ patches,
                                                   float* __restrict__ bias) {
  int n = blockIdx.x * 256 + threadIdx.x;
  if (n < N_) {
    const float* __restrict__ p = patches + n * PS;
    float s = 0.f;
#pragma unroll
    for (int j = 0; j < PS; j++) s += p[j] * p[j];
    bias[n] = 0.5f * s;
  }
}

// streaming top-8 insert, fully unrolled, register-resident arrays
__device__ __forceinline__ void insert8(float d, int idx, float td[KNN], int ti[KNN],
                                        float& tmax, int& tslot) {
  if (d < tmax) {
#pragma unroll
    for (int s = 0; s < KNN; s++) if (s == tslot) { td[s] = d; ti[s] = idx; }
    float m = td[0]; int ms = 0;
#pragma unroll
    for (int s = 1; s < KNN; s++) if (td[s] > m) { m = td[s]; ms = s; }
    tmax = m; tslot = ms;
  }
}

// ---------------------------------------------------------------------------
// Kernel 2: block = 256 threads = 4 waves, all sharing ONE group of 64 pixels.
// x-patches live in LDS (group-major float4: xv[g][pixel][4], lanes ->
// consecutive 16B -> conflict-free ds_read_b128), so the register live-set is
// genuinely ~50 VGPRs and the allocator has nothing to spill (rounds 1-2
// failure: xv[75] in VGPRs -> backend spilled to scratch, VALUBusy 37-76%).
// Each wave scans a 512-patch dictionary chunk; each LDS quad is reused
// across 8 patches so the LDS pipe (shared by 4 SIMDs) stays under 50%.
// Patch data is wave-uniform -> scalar-pipe s_loads, free SGPR operand in
// v_fma. Top-8 merge + epilogue reuse the xv LDS region.
// ---------------------------------------------------------------------------
__global__ __launch_bounds__(256)
void topk_kernel(const float* __restrict__ x, const float* __restrict__ patches,
                 const float* __restrict__ values, const float* __restrict__ bias,
                 float* __restrict__ out) {
  const int lane = threadIdx.x & 63;
  const int chunk = threadIdx.x >> 6;          // wave id = dictionary chunk
  const int pix = blockIdx.x * 64 + lane;
  const int w = pix & 63;
  const int h = (pix >> 6) & 63;
  const int b = pix >> 12;

  __shared__ float lds_x[19 * 256];            // 19456 B: [g][pixel][4] floats

  // ---- setup: wave `chunk` fills x-patch elements j in [19*chunk, 19*chunk+19) ----
#pragma unroll
  for (int t = 0; t < 19; t++) {
    const int j = chunk * 19 + t;              // 0..75 (j==75 is the pad lane)
    float v = 0.f;
    if (j < PS) {
      const int c = j / 25, r = j % 25, dh = r / 5, dw = r % 5;
      const int hh = h + dh - 2, ww = w + dw - 2;
      if ((unsigned)hh < 64u && (unsigned)ww < 64u)
        v = x[((b * C_ + c) * H_ + hh) * W_ + ww];
    }
    lds_x[(j >> 2) * 256 + lane * 4 + (j & 3)] = v;
  }
  __syncthreads();

  const float4* __restrict__ xq4 = (const float4*)lds_x;  // xq4[g*64 + lane]

  float td[KNN];
  int ti[KNN];
#pragma unroll
  for (int s = 0; s < KNN; s++) { td[s] = FLT_MAX; ti[s] = 0; }
  float tmax = FLT_MAX;
  int tslot = 0;

  // ---- main scan: 8 patches per iteration, one LDS quad feeds 32 FMAs ----
  const int nbase = chunk * NCHUNK;
#pragma unroll 1
  for (int i = 0; i < NCHUNK; i += QP) {
    const int n = nbase + i;
    const float* __restrict__ pb = patches + n * PS;  // wave-uniform base
    float acc[QP];
#pragma unroll
    for (int q = 0; q < QP; q++) acc[q] = 0.f;

#pragma unroll
    for (int g = 0; g < 18; g++) {
      const float4 xq = xq4[g * 64 + lane];
      const float xe[4] = {xq.x, xq.y, xq.z, xq.w};
#pragma unroll
      for (int e = 0; e < 4; e++) {
#pragma unroll
        for (int q = 0; q < QP; q++)                 // q-major: 8 indep chains
          acc[q] = fmaf(pb[q * PS + 4 * g + e], xe[e], acc[q]);
      }
    }
    {  // g == 18: elements 72..74 only (75 is the pad)
      const float4 xq = xq4[18 * 64 + lane];
      const float xe[3] = {xq.x, xq.y, xq.z};
#pragma unroll
      for (int e = 0; e < 3; e++) {
#pragma unroll
        for (int q = 0; q < QP; q++)
          acc[q] = fmaf(pb[q * PS + 72 + e], xe[e], acc[q]);
      }
    }

    float d[QP];
#pragma unroll
    for (int q = 0; q < QP; q++) d[q] = bias[n + q] - acc[q];
    float m = d[0];
#pragma unroll
    for (int q = 1; q < QP; q++) m = fminf(m, d[q]);
    if (m < tmax) {
#pragma unroll
      for (int q = 0; q < QP; q++) insert8(d[q], n + q, td, ti, tmax, tslot);
    }
  }

  // ---- cross-wave merge (reuse lds_x region) ----
  float* __restrict__ md = lds_x;                    // [3][64][8] floats
  int* __restrict__ mi = (int*)(lds_x + 1536);       // [3][64][8] ints
  int* __restrict__ fi = (int*)(lds_x + 3072);       // [64][8] final indices

  __syncthreads();   // everyone done reading xv before overwrite
  if (chunk > 0) {
#pragma unroll
    for (int s = 0; s < KNN; s++) {
      md[(chunk - 1) * 512 + lane * 8 + s] = td[s];
      mi[(chunk - 1) * 512 + lane * 8 + s] = ti[s];
    }
  }
  __syncthreads();
  if (chunk == 0) {
#pragma unroll
    for (int mm = 0; mm < 3; mm++)
#pragma unroll
      for (int s = 0; s < KNN; s++)
        insert8(md[mm * 512 + lane * 8 + s], mi[mm * 512 + lane * 8 + s],
                td, ti, tmax, tslot);
#pragma unroll
    for (int s = 0; s < KNN; s++) fi[lane * 8 + s] = ti[s];
  }
  __syncthreads();

  // ---- epilogue: all 4 waves, wave `chunk` handles dims [32*chunk, 32*chunk+32) ----
  int base[KNN];
#pragma unroll
  for (int s = 0; s < KNN; s++) base[s] = fi[lane * 8 + s] * D_;
  const int obase = b * (D_ * H_ * W_) + h * W_ + w;
  const int d0 = chunk * 32;
#pragma unroll 1
  for (int dd = d0; dd < d0 + 32; dd += 4) {
    float s0 = 0.f, s1 = 0.f, s2 = 0.f, s3 = 0.f;
#pragma unroll
    for (int k = 0; k < KNN; k++) {
      const float4 v = *(const float4*)(values + base[k] + dd);
      s0 += v.x; s1 += v.y; s2 += v.z; s3 += v.w;
    }
    out[obase + (dd + 0) * (H_ * W_)] = s0 * 0.125f;
    out[obase + (dd + 1) * (H_ * W_)] = s1 * 0.125f;
    out[obase + (dd + 2) * (H_ * W_)] = s2 * 0.125f;
    out[obase + (dd + 3) * (H_ * W_)] = s3 * 0.125f;
  }
}

// ---------------------------------------------------------------------------
extern "C" void kernel_launch(void* const* d_in, const int* in_sizes, int n_in,
                              void* d_out, int out_size, void* d_ws, size_t ws_size,
                              hipStream_t stream) {
  const float* x = (const float*)d_in[0];
  const float* patches = (const float*)d_in[1];
  const float* values = (const float*)d_in[2];
  float* out = (float*)d_out;
  float* bias = (float*)d_ws;  // 2048 floats of scratch

  hipLaunchKernelGGL(bias_kernel, dim3(N_ / 256), dim3(256), 0, stream, patches, bias);
  hipLaunchKernelGGL(topk_kernel, dim3((B_ * H_ * W_) / 64), dim3(256), 0, stream,
                     x, patches, values, bias, out);
}

// Round 4
// 1277.568 us; speedup vs baseline: 2.3008x; 2.3008x over previous
//
#include <hip/hip_runtime.h>
#include <float.h>

#define B_  32
#define C_  3
#define H_  64
#define W_  64
#define N_  2048
#define D_  128
#define KNN 8
#define PS  75        // 3*5*5
#define NW  4         // waves per block = dictionary chunks
#define NCHUNK (N_ / NW)   // 512 patches per wave
#define QP  8         // patches per inner iteration (xq reuse factor)

// ---------------------------------------------------------------------------
// Kernel 1: bias[n] = 0.5 * ||patches[n]||^2
// ---------------------------------------------------------------------------
__global__ __launch_bounds__(256) void bias_kernel(const float* __restrict__ patches,
                                                   float* __restrict__ bias) {
  int n = blockIdx.x * 256 + threadIdx.x;
  if (n < N_) {
    const float* __restrict__ p = patches + n * PS;
    float s = 0.f;
#pragma unroll
    for (int j = 0; j < PS; j++) s += p[j] * p[j];
    bias[n] = 0.5f * s;
  }
}

// streaming top-8 insert, fully unrolled, register-resident arrays
__device__ __forceinline__ void insert8(float d, int idx, float td[KNN], int ti[KNN],
                                        float& tmax, int& tslot) {
  if (d < tmax) {
#pragma unroll
    for (int s = 0; s < KNN; s++) if (s == tslot) { td[s] = d; ti[s] = idx; }
    float m = td[0]; int ms = 0;
#pragma unroll
    for (int s = 1; s < KNN; s++) if (td[s] > m) { m = td[s]; ms = s; }
    tmax = m; tslot = ms;
  }
}

// ---------------------------------------------------------------------------
// Kernel 2: block = 256 threads = 4 waves, all sharing ONE group of 64 pixels.
// x-patches live in LDS (group-major float4: lanes -> consecutive 16B ->
// conflict-free ds_read_b128); register live-set ~50 VGPRs, nothing to spill.
// Each wave scans a 512-patch dictionary chunk; each LDS quad is reused
// across 8 patches so the LDS pipe (shared by 4 SIMDs) stays under the VALU.
// CRITICAL (round-3 regression): `chunk` MUST go through readfirstlane —
// raw threadIdx.x>>6 is not proven wave-uniform, the patch pointer turns
// divergent, and 600 scalar-pipe s_loads/iter become 600 per-lane
// global_loads (SGPR 112->32, VALUBusy 76->26%, dur 894->2939 us).
// ---------------------------------------------------------------------------
__global__ __launch_bounds__(256)
void topk_kernel(const float* __restrict__ x, const float* __restrict__ patches,
                 const float* __restrict__ values, const float* __restrict__ bias,
                 float* __restrict__ out) {
  const int lane = threadIdx.x & 63;
  const int chunk = __builtin_amdgcn_readfirstlane(threadIdx.x >> 6);  // uniform!
  const int pix = blockIdx.x * 64 + lane;
  const int w = pix & 63;
  const int h = (pix >> 6) & 63;
  const int b = pix >> 12;

  __shared__ float lds_x[19 * 256];            // 19456 B: [g][pixel][4] floats

  // ---- setup: wave `chunk` fills x-patch elements j in [19*chunk, 19*chunk+19) ----
#pragma unroll
  for (int t = 0; t < 19; t++) {
    const int j = chunk * 19 + t;              // 0..75 (j==75 is the pad lane)
    float v = 0.f;
    if (j < PS) {
      const int c = j / 25, r = j % 25, dh = r / 5, dw = r % 5;
      const int hh = h + dh - 2, ww = w + dw - 2;
      if ((unsigned)hh < 64u && (unsigned)ww < 64u)
        v = x[((b * C_ + c) * H_ + hh) * W_ + ww];
    }
    lds_x[(j >> 2) * 256 + lane * 4 + (j & 3)] = v;
  }
  __syncthreads();

  const float4* __restrict__ xq4 = (const float4*)lds_x;  // xq4[g*64 + lane]

  float td[KNN];
  int ti[KNN];
#pragma unroll
  for (int s = 0; s < KNN; s++) { td[s] = FLT_MAX; ti[s] = 0; }
  float tmax = FLT_MAX;
  int tslot = 0;

  // ---- main scan: 8 patches per iteration, one LDS quad feeds 32 FMAs ----
  const int nbase = chunk * NCHUNK;            // uniform
#pragma unroll 1
  for (int i = 0; i < NCHUNK; i += QP) {
    const int n = nbase + i;
    const float* __restrict__ pb = patches + n * PS;  // wave-uniform base
    float acc[QP];
#pragma unroll
    for (int q = 0; q < QP; q++) acc[q] = 0.f;

#pragma unroll
    for (int g = 0; g < 18; g++) {
      const float4 xq = xq4[g * 64 + lane];
      const float xe[4] = {xq.x, xq.y, xq.z, xq.w};
#pragma unroll
      for (int e = 0; e < 4; e++) {
#pragma unroll
        for (int q = 0; q < QP; q++)                 // q-major: 8 indep chains
          acc[q] = fmaf(pb[q * PS + 4 * g + e], xe[e], acc[q]);
      }
    }
    {  // g == 18: elements 72..74 only (75 is the pad)
      const float4 xq = xq4[18 * 64 + lane];
      const float xe[3] = {xq.x, xq.y, xq.z};
#pragma unroll
      for (int e = 0; e < 3; e++) {
#pragma unroll
        for (int q = 0; q < QP; q++)
          acc[q] = fmaf(pb[q * PS + 72 + e], xe[e], acc[q]);
      }
    }

    float d[QP];
#pragma unroll
    for (int q = 0; q < QP; q++) d[q] = bias[n + q] - acc[q];
    float m = d[0];
#pragma unroll
    for (int q = 1; q < QP; q++) m = fminf(m, d[q]);
    if (m < tmax) {
#pragma unroll
      for (int q = 0; q < QP; q++) insert8(d[q], n + q, td, ti, tmax, tslot);
    }
  }

  // ---- cross-wave merge (reuse lds_x region) ----
  float* __restrict__ md = lds_x;                    // [3][64][8] floats
  int* __restrict__ mi = (int*)(lds_x + 1536);       // [3][64][8] ints
  int* __restrict__ fi = (int*)(lds_x + 3072);       // [64][8] final indices

  __syncthreads();   // everyone done reading xv before overwrite
  if (chunk > 0) {
#pragma unroll
    for (int s = 0; s < KNN; s++) {
      md[(chunk - 1) * 512 + lane * 8 + s] = td[s];
      mi[(chunk - 1) * 512 + lane * 8 + s] = ti[s];
    }
  }
  __syncthreads();
  if (chunk == 0) {
#pragma unroll
    for (int mm = 0; mm < 3; mm++)
#pragma unroll
      for (int s = 0; s < KNN; s++)
        insert8(md[mm * 512 + lane * 8 + s], mi[mm * 512 + lane * 8 + s],
                td, ti, tmax, tslot);
#pragma unroll
    for (int s = 0; s < KNN; s++) fi[lane * 8 + s] = ti[s];
  }
  __syncthreads();

  // ---- epilogue: all 4 waves, wave `chunk` handles dims [32*chunk, 32*chunk+32) ----
  int base[KNN];
#pragma unroll
  for (int s = 0; s < KNN; s++) base[s] = fi[lane * 8 + s] * D_;
  const int obase = b * (D_ * H_ * W_) + h * W_ + w;
  const int d0 = chunk * 32;
#pragma unroll 1
  for (int dd = d0; dd < d0 + 32; dd += 4) {
    float s0 = 0.f, s1 = 0.f, s2 = 0.f, s3 = 0.f;
#pragma unroll
    for (int k = 0; k < KNN; k++) {
      const float4 v = *(const float4*)(values + base[k] + dd);
      s0 += v.x; s1 += v.y; s2 += v.z; s3 += v.w;
    }
    out[obase + (dd + 0) * (H_ * W_)] = s0 * 0.125f;
    out[obase + (dd + 1) * (H_ * W_)] = s1 * 0.125f;
    out[obase + (dd + 2) * (H_ * W_)] = s2 * 0.125f;
    out[obase + (dd + 3) * (H_ * W_)] = s3 * 0.125f;
  }
}

// ---------------------------------------------------------------------------
extern "C" void kernel_launch(void* const* d_in, const int* in_sizes, int n_in,
                              void* d_out, int out_size, void* d_ws, size_t ws_size,
                              hipStream_t stream) {
  const float* x = (const float*)d_in[0];
  const float* patches = (const float*)d_in[1];
  const float* values = (const float*)d_in[2];
  float* out = (float*)d_out;
  float* bias = (float*)d_ws;  // 2048 floats of scratch

  hipLaunchKernelGGL(bias_kernel, dim3(N_ / 256), dim3(256), 0, stream, patches, bias);
  hipLaunchKernelGGL(topk_kernel, dim3((B_ * H_ * W_) / 64), dim3(256), 0, stream,
                     x, patches, values, bias, out);
}

// Round 5
// 918.887 us; speedup vs baseline: 3.1990x; 1.3903x over previous
//
#include <hip/hip_runtime.h>
#include <float.h>

#define B_  32
#define C_  3
#define H_  64
#define W_  64
#define N_  2048
#define D_  128
#define KNN 8
#define PS  75        // 3*5*5
#define NCHUNK 1024   // dictionary patches per wave (2-way split)
#define QP  8         // distances per top-k batch check

// ---------------------------------------------------------------------------
// Kernel 1: bias[n] = 0.5 * ||patches[n]||^2
// ---------------------------------------------------------------------------
__global__ __launch_bounds__(256) void bias_kernel(const float* __restrict__ patches,
                                                   float* __restrict__ bias) {
  int n = blockIdx.x * 256 + threadIdx.x;
  if (n < N_) {
    const float* __restrict__ p = patches + n * PS;
    float s = 0.f;
#pragma unroll
    for (int j = 0; j < PS; j++) s += p[j] * p[j];
    bias[n] = 0.5f * s;
  }
}

// streaming top-8 insert, fully unrolled, register-resident arrays
__device__ __forceinline__ void insert8(float d, int idx, float td[KNN], int ti[KNN],
                                        float& tmax, int& tslot) {
  if (d < tmax) {
#pragma unroll
    for (int s = 0; s < KNN; s++) if (s == tslot) { td[s] = d; ti[s] = idx; }
    float m = td[0]; int ms = 0;
#pragma unroll
    for (int s = 1; s < KNN; s++) if (td[s] > m) { m = td[s]; ms = s; }
    tmax = m; tslot = ms;
  }
}

// ---------------------------------------------------------------------------
// Kernel 2: block = 256 = 4 waves = 2 pixel-groups x 2 dictionary chunks.
// KEY (round-4 lessons):
//  * xv[75] lives in VGPRs. The allocator budgets VGPRs from the
//    LDS-derived occupancy: 40960 B/block -> 4 blocks/CU -> 4 waves/SIMD
//    -> 128-VGPR budget, so xv is NOT spilled (rounds 1/2: 19KB LDS or
//    less -> 8-wave target -> 64-VGPR budget -> spills, VGPR_Count 52-56).
//  * NO ds_read in the hot loop: ds_read shares lgkmcnt with s_load, and
//    every lgkmcnt(0) for LDS drained the SMEM prefetch queue (round 4:
//    VALUBusy 65%, dur 1277).
//  * Patch rows consumed PAIR-wise (2 rows live = ~32 dwords of SGPR
//    payload), not 8-wide (round 4's q-inner needed 600 live dwords ->
//    un-pipelineable). 4 independent FMA chains cover the 4-cyc FMA latency.
//  * chunk/pgrp derived via readfirstlane -> provably wave-uniform patch
//    pointer -> scalar-pipe s_loads (round-3 regression: divergent pointer,
//    SGPR 112->32, dur 2939).
// ---------------------------------------------------------------------------
__global__ __launch_bounds__(256)
void topk_kernel(const float* __restrict__ x, const float* __restrict__ patches,
                 const float* __restrict__ values, const float* __restrict__ bias,
                 float* __restrict__ out) {
  const int lane = threadIdx.x & 63;
  const int wid = __builtin_amdgcn_readfirstlane(threadIdx.x >> 6);  // uniform
  const int chunk = wid & 1;   // dictionary half
  const int pgrp = wid >> 1;   // pixel group within block
  const int pix = blockIdx.x * 128 + pgrp * 64 + lane;
  const int w = pix & 63;
  const int h = (pix >> 6) & 63;
  const int b = pix >> 12;

  // 40960 B: occupancy governor (4 blocks/CU) + merge scratch at the front.
  __shared__ float lds_buf[10240];

  // ---- x-patch (75 floats) into REGISTERS, zero-padded (PAD=2) ----
  float xv[PS];
#pragma unroll
  for (int c = 0; c < C_; c++) {
#pragma unroll
    for (int dh = 0; dh < 5; dh++) {
      const int hh = h + dh - 2;
#pragma unroll
      for (int dw = 0; dw < 5; dw++) {
        const int ww = w + dw - 2;
        const bool ok = ((unsigned)hh < 64u) && ((unsigned)ww < 64u);
        xv[(c * 5 + dh) * 5 + dw] = ok ? x[((b * C_ + c) * H_ + hh) * W_ + ww] : 0.f;
      }
    }
  }

  float td[KNN];
  int ti[KNN];
#pragma unroll
  for (int s = 0; s < KNN; s++) { td[s] = FLT_MAX; ti[s] = 0; }
  float tmax = FLT_MAX;
  int tslot = 0;

  // ---- main scan: 8 distances per batch check, rows consumed pair-wise ----
  const int nbase = chunk * NCHUNK;
#pragma unroll 1
  for (int i = 0; i < NCHUNK; i += QP) {
    const int n = nbase + i;
    float d[QP];
#pragma unroll
    for (int qq = 0; qq < QP; qq += 2) {
      const float* __restrict__ p0 = patches + (n + qq) * PS;  // uniform base
      const float* __restrict__ p1 = p0 + PS;
      float a0 = 0.f, a1 = 0.f, b0 = 0.f, b1 = 0.f;
#pragma unroll
      for (int j = 0; j < 37; j++) {
        a0 = fmaf(p0[2 * j],     xv[2 * j],     a0);
        b0 = fmaf(p0[2 * j + 1], xv[2 * j + 1], b0);
        a1 = fmaf(p1[2 * j],     xv[2 * j],     a1);
        b1 = fmaf(p1[2 * j + 1], xv[2 * j + 1], b1);
      }
      a0 = fmaf(p0[74], xv[74], a0);
      a1 = fmaf(p1[74], xv[74], a1);
      d[qq]     = bias[n + qq]     - (a0 + b0);
      d[qq + 1] = bias[n + qq + 1] - (a1 + b1);
    }
    float m = d[0];
#pragma unroll
    for (int q = 1; q < QP; q++) m = fminf(m, d[q]);
    if (m < tmax) {
#pragma unroll
      for (int q = 0; q < QP; q++) insert8(d[q], n + q, td, ti, tmax, tslot);
    }
  }

  // ---- cross-wave merge (chunk 1 -> chunk 0) via LDS front region ----
  float* __restrict__ md = lds_buf;                  // [2][64][8] floats
  int* __restrict__ mi = (int*)(lds_buf + 1024);     // [2][64][8] ints
  int* __restrict__ fi = (int*)(lds_buf + 2048);     // [2][64][8] final idx

  if (chunk == 1) {
#pragma unroll
    for (int s = 0; s < KNN; s++) {
      md[pgrp * 512 + lane * 8 + s] = td[s];
      mi[pgrp * 512 + lane * 8 + s] = ti[s];
    }
  }
  __syncthreads();
  if (chunk == 0) {
#pragma unroll
    for (int s = 0; s < KNN; s++)
      insert8(md[pgrp * 512 + lane * 8 + s], mi[pgrp * 512 + lane * 8 + s],
              td, ti, tmax, tslot);
#pragma unroll
    for (int s = 0; s < KNN; s++) fi[pgrp * 512 + lane * 8 + s] = ti[s];
  }
  __syncthreads();

  // ---- epilogue: both waves of the pixel group; wave `chunk` does 64 dims ----
  int base[KNN];
#pragma unroll
  for (int s = 0; s < KNN; s++) base[s] = fi[pgrp * 512 + lane * 8 + s] * D_;
  const int obase = b * (D_ * H_ * W_) + h * W_ + w;
  const int d0 = chunk * 64;
#pragma unroll 1
  for (int dd = d0; dd < d0 + 64; dd += 4) {
    float s0 = 0.f, s1 = 0.f, s2 = 0.f, s3 = 0.f;
#pragma unroll
    for (int k = 0; k < KNN; k++) {
      const float4 v = *(const float4*)(values + base[k] + dd);
      s0 += v.x; s1 += v.y; s2 += v.z; s3 += v.w;
    }
    out[obase + (dd + 0) * (H_ * W_)] = s0 * 0.125f;
    out[obase + (dd + 1) * (H_ * W_)] = s1 * 0.125f;
    out[obase + (dd + 2) * (H_ * W_)] = s2 * 0.125f;
    out[obase + (dd + 3) * (H_ * W_)] = s3 * 0.125f;
  }
}

// ---------------------------------------------------------------------------
extern "C" void kernel_launch(void* const* d_in, const int* in_sizes, int n_in,
                              void* d_out, int out_size, void* d_ws, size_t ws_size,
                              hipStream_t stream) {
  const float* x = (const float*)d_in[0];
  const float* patches = (const float*)d_in[1];
  const float* values = (const float*)d_in[2];
  float* out = (float*)d_out;
  float* bias = (float*)d_ws;  // 2048 floats of scratch

  hipLaunchKernelGGL(bias_kernel, dim3(N_ / 256), dim3(256), 0, stream, patches, bias);
  hipLaunchKernelGGL(topk_kernel, dim3((B_ * H_ * W_) / 128), dim3(256), 0, stream,
                     x, patches, values, bias, out);
}